// Round 16
// baseline (214.475 us; speedup 1.0000x reference)
//
#include <hip/hip_runtime.h>
#include <hip/hip_bf16.h>

// B=8 S=256 H=768 D=128 L=64, all inputs f32.
// Outputs: relate_score (8*64) | lm_b (8*64*128) | lc_b (8*64*128*128), f32.

#define PITCH 132

typedef __attribute__((ext_vector_type(8))) short bf16x8;
typedef __attribute__((ext_vector_type(4))) float f32x4;

__device__ __forceinline__ float bf2f(unsigned int u) {
    union { unsigned int i; float f; } c; c.i = u << 16; return c.f;
}
__device__ __forceinline__ unsigned short f2bf(float f) {
    __hip_bfloat16 h = __float2bfloat16(f);
    union { __hip_bfloat16 h; unsigned short u; } c; c.h = h; return c.u;
}

// ---------------------------------------------------------------- K1: wm/wv GEMM (+ bf16 wv^T) + sm/sv (x==256) + label scalars (x==257)
// A staged once in LDS (772 pitch: conflict-free 8-row broadcast); W read register-direct
// (row k is 512B coalesced, L1/L2-hot — every block streams the same W). 1 barrier total.
__global__ __launch_bounds__(256, 2)
void k1_gemm(const float* __restrict__ Am, const float* __restrict__ Av,
             const float* __restrict__ sfm, const float* __restrict__ sfd,
             const float* __restrict__ W1, const float* __restrict__ B1,
             const float* __restrict__ W2, const float* __restrict__ B2,
             const float* __restrict__ W3, const float* __restrict__ B3,
             const float* __restrict__ W4, const float* __restrict__ B4,
             const float* __restrict__ lm, const float* __restrict__ ldv,
             float* __restrict__ wm, float* __restrict__ wv,
             float* __restrict__ sm, float* __restrict__ sv,
             float4* __restrict__ labscg,
             unsigned short* __restrict__ wvTg) {
    const int tid = threadIdx.x;
    const int sel = blockIdx.y;
    if (blockIdx.x == 257) {           // label scalars: mmp, |v|^2, vmp per label
        if (sel == 0) {
            int l = tid >> 2, q = tid & 3;
            const float* mr = lm + (size_t)l * 128 + q * 32;
            const float* vr = ldv + (size_t)l * 128 + q * 32;
            float s0 = 0.f, s1 = 0.f, s2 = 0.f;
            for (int k = 0; k < 32; k += 4) {
                float4 m = *(const float4*)&mr[k];
                float4 v = *(const float4*)&vr[k];
                s0 += m.x * m.x + m.y * m.y + m.z * m.z + m.w * m.w;
                s1 += v.x * v.x + v.y * v.y + v.z * v.z + v.w * v.w;
                s2 += m.x * v.x + m.y * v.y + m.z * v.z + m.w * v.w;
            }
            s0 += __shfl_xor(s0, 1); s0 += __shfl_xor(s0, 2);
            s1 += __shfl_xor(s1, 1); s1 += __shfl_xor(s1, 2);
            s2 += __shfl_xor(s2, 1); s2 += __shfl_xor(s2, 2);
            if (q == 0) labscg[l] = make_float4(s0, s1, s2, 0.f);
        }
        return;
    }
    __shared__ float At[8][772];       // 772 pitch: (4r+k)%32 distinct for r<8 -> no bank conflict
    __shared__ float tileT[8][129];
    const bool sentB = (blockIdx.x == 256);
    const float* A  = sentB ? (sel ? sfd : sfm) : (sel ? Av : Am);
    const float* W  = sentB ? (sel ? W4 : W3) : (sel ? W2 : W1);
    const float* Bs = sentB ? (sel ? B4 : B3) : (sel ? B2 : B1);
    float* D = sentB ? (sel ? sv : sm) : (sel ? wv : wm);
    const int R0 = sentB ? 0 : blockIdx.x * 8;
    // stage A once: 8 rows x 768, coalesced
#pragma unroll
    for (int rr = 0; rr < 8; ++rr)
        for (int cc = tid; cc < 768; cc += 256)
            At[rr][cc] = A[(size_t)(R0 + rr) * 768 + cc];
    __syncthreads();
    const int r = tid >> 5;
    const int j0 = (tid & 31) * 4;
    float a0 = 0.f, a1 = 0.f, a2 = 0.f, a3 = 0.f;
#pragma unroll 8
    for (int k = 0; k < 768; ++k) {
        float a = At[r][k];
        float4 w = *(const float4*)&W[(size_t)k * 128 + j0];
        a0 += a * w.x; a1 += a * w.y; a2 += a * w.z; a3 += a * w.w;
    }
    {
        float4 o = make_float4(a0 + Bs[j0], a1 + Bs[j0 + 1], a2 + Bs[j0 + 2], a3 + Bs[j0 + 3]);
        *(float4*)&D[(size_t)(R0 + r) * 128 + j0] = o;
        tileT[r][j0 + 0] = o.x; tileT[r][j0 + 1] = o.y;
        tileT[r][j0 + 2] = o.z; tileT[r][j0 + 3] = o.w;
    }
    if (sel && !sentB) {
        __syncthreads();
        if (tid < 128) {
            int d = tid;
            unsigned short u[8];
#pragma unroll
            for (int ss = 0; ss < 8; ++ss) u[ss] = f2bf(tileT[ss][d]);
            unsigned int p0 = (unsigned int)u[0] | ((unsigned int)u[1] << 16);
            unsigned int p1 = (unsigned int)u[2] | ((unsigned int)u[3] << 16);
            unsigned int p2 = (unsigned int)u[4] | ((unsigned int)u[5] << 16);
            unsigned int p3 = (unsigned int)u[6] | ((unsigned int)u[7] << 16);
            unsigned short* dst = wvTg + (size_t)(R0 >> 8) * 32768 + (size_t)d * 256 + (R0 & 255);
            *(uint4*)dst = make_uint4(p0, p1, p2, p3);
        }
    }
}

// ---------------------------------------------------------------- batched block reduce (4 waves), one barrier set
template <int N>
__device__ __forceinline__ void bsumN(float* v, float* red) {
#pragma unroll
    for (int o = 32; o; o >>= 1)
#pragma unroll
        for (int n = 0; n < N; ++n) v[n] += __shfl_xor(v[n], o);
    __syncthreads();
    if ((threadIdx.x & 63) == 0) {
        int w = threadIdx.x >> 6;
#pragma unroll
        for (int n = 0; n < N; ++n) red[w * N + n] = v[n];
    }
    __syncthreads();
#pragma unroll
    for (int n = 0; n < N; ++n)
        v[n] = red[0 * N + n] + red[1 * N + n] + red[2 * N + n] + red[3 * N + n];
    __syncthreads();
}

// ---------------------------------------------------------------- K4: fused; 2-barrier lookahead Cholesky + recursive-doubling inverse.
__global__ __launch_bounds__(256, 2)
void k4_fused(const float* __restrict__ wm, const float* __restrict__ wv,
              const unsigned short* __restrict__ wvTg,
              const float* __restrict__ smg, const float* __restrict__ svg,
              const float* __restrict__ lmg, const float* __restrict__ ldvg,
              const float4* __restrict__ labscg,
              float* __restrict__ out) {
    extern __shared__ float smem[];
    float* Amat = smem;                 // 16896 f32
    float* Wb   = smem + 16896;         // 2112 (RD temp alias)
    float* ssq  = smem + 19008;         // 256
    float* svr  = smem + 19264;         // 128
    float* vrow = smem + 19392;         // 128
    float* zv   = smem + 19520;         // 128  (mu until delta built)
    float* zd   = smem + 19648;         // 128
    float* red  = smem + 19776;         // 24
    float* scoreL = Amat;               // 256 (pre-staging only)
    float* vpart  = Amat + 256;         // 1024 (pre-staging only)

    const int tid = threadIdx.x;
    const int bid = blockIdx.x;
    const int b = bid >> 6, l = bid & 63;

    if (tid < 128) {
        svr[tid]  = svg[b * 128 + tid];
        vrow[tid] = ldvg[l * 128 + tid];
        zv[tid]   = lmg[l * 128 + tid];     // mu (temporary)
    }
    __syncthreads();
    // ---- early output writes: lm_b[b][l], lc_b[b][l]
    if (tid < 32) {
        float4 v = *(const float4*)&lmg[l * 128 + tid * 4];
        *(float4*)&out[512 + (size_t)bid * 128 + tid * 4] = v;
    }
    {
        float* lcb = out + 512 + 65536 + (size_t)bid * 16384;
#pragma unroll
        for (int q = 0; q < 16; ++q) {
            int flat4 = q * 256 + tid;
            int i = flat4 >> 5;
            int j4 = (flat4 & 31) * 4;
            float vi = vrow[i];
            float4 r;
            r.x = vi * vrow[j4 + 0] + ((i == j4 + 0) ? 1.f : 0.f);
            r.y = vi * vrow[j4 + 1] + ((i == j4 + 1) ? 1.f : 0.f);
            r.z = vi * vrow[j4 + 2] + ((i == j4 + 2) ? 1.f : 0.f);
            r.w = vi * vrow[j4 + 3] + ((i == j4 + 3) ? 1.f : 0.f);
            *(float4*)&lcb[(size_t)flat4 * 4] = r;
        }
    }
    // ---- phase 0a: label scalars (precomputed in k1)
    float4 lsv = labscg[l];
    const float mmp = lsv.x, np = 1.f + lsv.y, vmp = lsv.z;
    // ---- phase 0b: per-row dots + row scalars (thread = s)
    const float4* wmr = (const float4*)(wm + (size_t)(b * 256 + tid) * 128);
    const float4* wvr = (const float4*)(wv + (size_t)(b * 256 + tid) * 128);
    float md = 0.f, dot = 0.f, pvv = 0.f, vq = 0.f;
    float smm = 0.f, svv = 0.f, smv = 0.f;
#pragma unroll 8
    for (int q = 0; q < 32; ++q) {
        float4 xm = wmr[q], xv = wvr[q];
        const float* m4 = &zv[q * 4];
        const float* v4 = &vrow[q * 4];
        md  += m4[0] * xm.x + m4[1] * xm.y + m4[2] * xm.z + m4[3] * xm.w;
        dot += v4[0] * xv.x + v4[1] * xv.y + v4[2] * xv.z + v4[3] * xv.w;
        pvv += m4[0] * xv.x + m4[1] * xv.y + m4[2] * xv.z + m4[3] * xv.w;
        vq  += v4[0] * xm.x + v4[1] * xm.y + v4[2] * xm.z + v4[3] * xm.w;
        smm += xm.x * xm.x + xm.y * xm.y + xm.z * xm.z + xm.w * xm.w;
        svv += xv.x * xv.x + xv.y * xv.y + xv.z * xv.z + xv.w * xv.w;
        smv += xm.x * xv.x + xm.y * xv.y + xm.z * xv.z + xm.w * xv.w;
    }
    float nq = 1.f + svv;
    float d2 = smm - 2.f * md + mmp;
    float vqd = smv - pvv, vpd = vq - vmp;
    float inq = 1.f / nq, inp = 1.f / np;
    float maha_q = d2 - vqd * vqd * inq;
    float maha_p = d2 - vpd * vpd * inp;
    float logit = 0.25f * ((np - 1.f) + (nq - 1.f)
                           - (nq - 1.f + dot * dot) * inq
                           - (np - 1.f + dot * dot) * inp
                           + maha_q + maha_p);
    // ---- phase 0c: softmax over 256 threads (2 barriers: distinct red slots)
    float mx = logit;
#pragma unroll
    for (int o = 32; o; o >>= 1) mx = fmaxf(mx, __shfl_xor(mx, o));
    if ((tid & 63) == 0) red[tid >> 6] = mx;
    __syncthreads();
    mx = fmaxf(fmaxf(red[0], red[1]), fmaxf(red[2], red[3]));
    float e = expf(logit - mx);
    float s = e;
#pragma unroll
    for (int o = 32; o; o >>= 1) s += __shfl_xor(s, o);
    if ((tid & 63) == 0) red[8 + (tid >> 6)] = s;
    __syncthreads();
    float tot = red[8] + red[9] + red[10] + red[11];
    float sc = e / tot;
    scoreL[tid] = sc;
    ssq[tid] = sqrtf(sc);
    __syncthreads();
    // ---- phase 0d: v_mean = score @ wm
    {
        int d4 = (tid & 31) * 4, sg = tid >> 5;
        const float* wmb = wm + (size_t)b * 256 * 128;
        float ax = 0.f, ay = 0.f, az = 0.f, aw = 0.f;
        for (int s2 = sg * 32; s2 < sg * 32 + 32; ++s2) {
            float w = scoreL[s2];
            float4 x = *(const float4*)&wmb[(size_t)s2 * 128 + d4];
            ax += w * x.x; ay += w * x.y; az += w * x.z; aw += w * x.w;
        }
        *(float4*)&vpart[sg * 128 + d4] = make_float4(ax, ay, az, aw);
    }
    __syncthreads();
    if (tid < 128) {
        float vm8 = 0.f;
#pragma unroll
        for (int g2 = 0; g2 < 8; ++g2) vm8 += vpart[g2 * 128 + tid];
        zd[tid] = zv[tid] - 0.5f * (smg[b * 128 + tid] + vm8);  // delta
        zv[tid] = vrow[tid];                                     // rhs v
    }
    __syncthreads();
    // ---- phase 1a: stage S^T (bf16, rows d, 264-bf16 pitch), scaled by sqrt(score)
    {
        unsigned short* Sb = (unsigned short*)Amat;
        const unsigned short* src = wvTg + (size_t)b * 32768;
        const int s0 = (tid & 31) * 8;
        float ssv[8];
#pragma unroll
        for (int j = 0; j < 8; ++j) ssv[j] = ssq[s0 + j];
#pragma unroll
        for (int it = 0; it < 16; ++it) {
            int f8 = tid + it * 256;
            int d = f8 >> 5;
            uint4 raw = *(const uint4*)&src[(size_t)f8 * 8];
            unsigned int p0 = (unsigned int)f2bf(bf2f(raw.x & 0xffffu) * ssv[0])
                            | ((unsigned int)f2bf(bf2f(raw.x >> 16) * ssv[1]) << 16);
            unsigned int p1 = (unsigned int)f2bf(bf2f(raw.y & 0xffffu) * ssv[2])
                            | ((unsigned int)f2bf(bf2f(raw.y >> 16) * ssv[3]) << 16);
            unsigned int p2 = (unsigned int)f2bf(bf2f(raw.z & 0xffffu) * ssv[4])
                            | ((unsigned int)f2bf(bf2f(raw.z >> 16) * ssv[5]) << 16);
            unsigned int p3 = (unsigned int)f2bf(bf2f(raw.w & 0xffffu) * ssv[6])
                            | ((unsigned int)f2bf(bf2f(raw.w >> 16) * ssv[7]) << 16);
            *(uint4*)&Sb[(size_t)d * 264 + s0] = make_uint4(p0, p1, p2, p3);
        }
    }
    __syncthreads();
    // ---- phase 1b: M = S^T S via MFMA; wave w computes tile-rows w and w+4
    {
        const unsigned short* Sb = (const unsigned short*)Amat;
        const int w = tid >> 6, ln = tid & 63;
        const int rl = ln & 15, g = ln >> 4;
        const int arow0 = 16 * w + rl;
        const int arow1 = 16 * (w + 4) + rl;
        f32x4 acc0[8], acc1[8];
#pragma unroll
        for (int t = 0; t < 8; ++t) {
            acc0[t] = (f32x4){0.f, 0.f, 0.f, 0.f};
            acc1[t] = (f32x4){0.f, 0.f, 0.f, 0.f};
        }
#pragma unroll
        for (int ks = 0; ks < 8; ++ks) {
            bf16x8 a0 = *(const bf16x8*)&Sb[(size_t)arow0 * 264 + ks * 32 + g * 8];
            bf16x8 a1 = *(const bf16x8*)&Sb[(size_t)arow1 * 264 + ks * 32 + g * 8];
#pragma unroll
            for (int tj = 0; tj < 8; ++tj) {
                bf16x8 bb = *(const bf16x8*)&Sb[(size_t)(16 * tj + rl) * 264 + ks * 32 + g * 8];
                acc0[tj] = __builtin_amdgcn_mfma_f32_16x16x32_bf16(a0, bb, acc0[tj], 0, 0, 0);
                acc1[tj] = __builtin_amdgcn_mfma_f32_16x16x32_bf16(a1, bb, acc1[tj], 0, 0, 0);
            }
        }
        __syncthreads();
#pragma unroll
        for (int tj = 0; tj < 8; ++tj) {
            int j = 16 * tj + rl;
            float svj = svr[j];
#pragma unroll
            for (int r = 0; r < 4; ++r) {
                int i = 16 * w + g * 4 + r;
                Amat[i * PITCH + j] = ((i == j) ? 1.f : 0.f) + 0.5f * (svr[i] * svj + acc0[tj][r]);
                int i2 = 16 * (w + 4) + g * 4 + r;
                Amat[i2 * PITCH + j] = ((i2 == j) ? 1.f : 0.f) + 0.5f * (svr[i2] * svj + acc1[tj][r]);
            }
        }
    }
    __syncthreads();
    // ---- phase 2c: label-side closed-form terms, one batched reduction
    float v5[5] = {0.f, 0.f, 0.f, 0.f, 0.f};
    if (tid < 128) {
        v5[0] = Amat[tid * PITCH + tid];
        float vv = vrow[tid], de = zd[tid];
        v5[1] = vv * vv; v5[2] = de * de; v5[3] = vv * de;
    }
    {
        int i = tid >> 1, h = tid & 1;
        const float* Ar = &Amat[i * PITCH + h * 64];
        const float* vr = &vrow[h * 64];
        float s2 = 0.f;
        for (int k2 = 0; k2 < 64; k2 += 4) {
            float4 a = *(const float4*)&Ar[k2];
            s2 += a.x * vr[k2] + a.y * vr[k2 + 1] + a.z * vr[k2 + 2] + a.w * vr[k2 + 3];
        }
        v5[4] = vrow[i] * s2;
    }
    bsumN<5>(v5, red);
    const float trP = v5[0], nv = v5[1], dds = v5[2], vds = v5[3], vsv = v5[4];
    // ---- phase 3: blocked Cholesky, 2 barriers/panel.
    for (int p = 0; p < 8; ++p) {
        const int base = 16 * p;
        const int R = 112 - base;
        __syncthreads();                         // solve(p-1)/Wb(p-1)/z'(p-1) visible
        if (tid < 64) {
            const int c = tid;
            float cv[16];
            if (c < 16) {
#pragma unroll
                for (int r2 = 0; r2 < 16; ++r2) {
                    int hi = (r2 >= c) ? r2 : c, lo2 = (r2 >= c) ? c : r2;
                    cv[r2] = Amat[(base + hi) * PITCH + base + lo2];
                }
                if (p > 0) {
                    float wbc[16];
#pragma unroll
                    for (int t = 0; t < 16; ++t) wbc[t] = Wb[t * PITCH + base + c];
#pragma unroll
                    for (int r2 = 0; r2 < 16; ++r2) {
                        float acc2 = 0.f;
#pragma unroll
                        for (int t = 0; t < 16; ++t)
                            acc2 += __shfl(wbc[t], r2) * wbc[t];
                        cv[r2] -= acc2;
                    }
                }
            } else {
#pragma unroll
                for (int r2 = 0; r2 < 16; ++r2) cv[r2] = 0.f;
            }
#pragma unroll
            for (int t = 0; t < 16; ++t) {
                float lt[16];
#pragma unroll
                for (int r2 = 0; r2 < 16; ++r2) lt[r2] = __shfl(cv[r2], t);
                float invs = 1.f / sqrtf(lt[t]);
                if (c == t) {
#pragma unroll
                    for (int r2 = 0; r2 < 16; ++r2) cv[r2] = (r2 >= t) ? lt[r2] * invs : 0.f;
                } else if (c > t && c < 16) {
                    float lc = lt[c] * invs;
#pragma unroll
                    for (int r2 = 0; r2 < 16; ++r2)
                        if (r2 > t) cv[r2] -= (lt[r2] * invs) * lc;
                }
            }
            float x[16], acb[16];
#pragma unroll
            for (int r2 = 0; r2 < 16; ++r2) acb[r2] = 0.f;
#pragma unroll
            for (int r2 = 0; r2 < 16; ++r2) {
                float Lrr = __shfl(cv[r2], r2);
                float xr = (((c == r2) ? 1.f : 0.f) - acb[r2]) / Lrr;
                x[r2] = xr;
#pragma unroll
                for (int q = r2 + 1; q < 16; ++q) acb[q] += __shfl(cv[q], r2) * xr;
            }
            if (c < 16) {
#pragma unroll
                for (int r2 = 0; r2 < 16; ++r2)
                    Amat[(base + c) * PITCH + base + r2] = x[r2];   // T^T into diag block
            }
        } else if (p > 0) {
            const int pb = base - 16;
            int t = tid - 64;                    // 0..191
            if (t < 128 - base) {                // z trailing update, rows base..127
                int i = base + t;
                const float* Lr = &Amat[i * PITCH + pb];
                float dv = 0.f, dd2 = 0.f;
#pragma unroll
                for (int t2 = 0; t2 < 16; ++t2) {
                    float lvv = Lr[t2];
                    dv  += lvv * zv[pb + t2];
                    dd2 += lvv * zd[pb + t2];
                }
                zv[i] -= dv; zd[i] -= dd2;
            }
            // U_col-below: rows base+16..127, cols base..base+15
            for (int idx = t; idx < R * 16; idx += 192) {
                int r2 = idx >> 4, jc = idx & 15;
                int i = base + 16 + r2, j = base + jc;
                const float* wi = &Wb[i];
                const float* wj = &Wb[j];
                float acc2 = 0.f;
#pragma unroll
                for (int t2 = 0; t2 < 16; ++t2)
                    acc2 += wi[t2 * PITCH] * wj[t2 * PITCH];
                Amat[i * PITCH + j] -= acc2;
            }
            // U_rest: lower 8x8 tiles, rows/cols >= base+16
            if (R > 0) {
                int nt = R >> 3;
                int ntri = (nt * (nt + 1)) >> 1;
                for (int tau = t; tau < ntri; tau += 192) {
                    float ft = sqrtf(8.f * (float)tau + 1.f);
                    int tr = (int)((ft - 1.f) * 0.5f);
                    while (((tr + 1) * (tr + 2)) / 2 <= tau) ++tr;
                    while ((tr * (tr + 1)) / 2 > tau) --tr;
                    int tc = tau - ((tr * (tr + 1)) >> 1);
                    int ii = base + 16 + tr * 8, jj = base + 16 + tc * 8;
                    float a2[8][8];
#pragma unroll
                    for (int r2 = 0; r2 < 8; ++r2)
#pragma unroll
                        for (int c2 = 0; c2 < 8; ++c2) a2[r2][c2] = 0.f;
#pragma unroll
                    for (int t2 = 0; t2 < 16; ++t2) {
                        const float* wr = &Wb[t2 * PITCH];
                        float4 x0 = *(const float4*)&wr[ii];
                        float4 x1 = *(const float4*)&wr[ii + 4];
                        float4 y0 = *(const float4*)&wr[jj];
                        float4 y1 = *(const float4*)&wr[jj + 4];
                        float xa[8] = {x0.x,x0.y,x0.z,x0.w, x1.x,x1.y,x1.z,x1.w};
                        float yb[8] = {y0.x,y0.y,y0.z,y0.w, y1.x,y1.y,y1.z,y1.w};
#pragma unroll
                        for (int r2 = 0; r2 < 8; ++r2)
#pragma unroll
                            for (int c2 = 0; c2 < 8; ++c2) a2[r2][c2] += xa[r2] * yb[c2];
                    }
#pragma unroll
                    for (int r2 = 0; r2 < 8; ++r2) {
                        float* Ar2 = &Amat[(ii + r2) * PITCH + jj];
                        float4 u0 = *(float4*)&Ar2[0];
                        float4 u1 = *(float4*)&Ar2[4];
                        u0.x -= a2[r2][0]; u0.y -= a2[r2][1]; u0.z -= a2[r2][2]; u0.w -= a2[r2][3];
                        u1.x -= a2[r2][4]; u1.y -= a2[r2][5]; u1.z -= a2[r2][6]; u1.w -= a2[r2][7];
                        *(float4*)&Ar2[0] = u0;
                        *(float4*)&Ar2[4] = u1;
                    }
                }
            }
        }
        __syncthreads();                         // T ready; updates applied
        if (R > 0 && tid < R) {
            int i = base + 16 + tid;
            const float* Ar = &Amat[i * PITCH + base];
            float4 q0 = *(const float4*)&Ar[0];
            float4 q1 = *(const float4*)&Ar[4];
            float4 q2 = *(const float4*)&Ar[8];
            float4 q3 = *(const float4*)&Ar[12];
            float rA[16] = {q0.x,q0.y,q0.z,q0.w, q1.x,q1.y,q1.z,q1.w,
                            q2.x,q2.y,q2.z,q2.w, q3.x,q3.y,q3.z,q3.w};
            float lo[16];
#pragma unroll
            for (int t = 0; t < 16; ++t) lo[t] = 0.f;
#pragma unroll
            for (int a = 0; a < 16; ++a) {
                float va = rA[a];
                const float* Trow = &Amat[(base + a) * PITCH + base];
                float4 t0 = *(const float4*)&Trow[0];
                float4 t1 = *(const float4*)&Trow[4];
                float4 t2 = *(const float4*)&Trow[8];
                float4 t3 = *(const float4*)&Trow[12];
                lo[0] += va * t0.x; lo[1] += va * t0.y; lo[2] += va * t0.z; lo[3] += va * t0.w;
                lo[4] += va * t1.x; lo[5] += va * t1.y; lo[6] += va * t1.z; lo[7] += va * t1.w;
                lo[8] += va * t2.x; lo[9] += va * t2.y; lo[10] += va * t2.z; lo[11] += va * t2.w;
                lo[12] += va * t3.x; lo[13] += va * t3.y; lo[14] += va * t3.z; lo[15] += va * t3.w;
            }
            float* Aw = &Amat[i * PITCH + base];
            *(float4*)&Aw[0]  = make_float4(lo[0], lo[1], lo[2], lo[3]);
            *(float4*)&Aw[4]  = make_float4(lo[4], lo[5], lo[6], lo[7]);
            *(float4*)&Aw[8]  = make_float4(lo[8], lo[9], lo[10], lo[11]);
            *(float4*)&Aw[12] = make_float4(lo[12], lo[13], lo[14], lo[15]);
#pragma unroll
            for (int t = 0; t < 16; ++t) Wb[t * PITCH + i] = lo[t];
        }
        if (tid >= 128 && tid < 160) {           // z' = T * z_panel (wave 2, lockstep)
            int t2 = (tid - 128) & 15;
            float* zp = (tid < 144) ? zv : zd;
            float a0 = 0.f;
#pragma unroll
            for (int a = 0; a < 16; ++a)
                a0 += Amat[(base + a) * PITCH + base + t2] * zp[base + a];
            zp[base + t2] = a0;
        }
    }
    // ---- phase 3b: X = L^{-1} via RECURSIVE DOUBLING (16 -> 32 -> 64 -> 128).
    __syncthreads();
    // Level 1: pairs q=0..3
    for (int t = tid; t < 128; t += 256) {   // step A: Yt = (L21*T1)^T
        int q = t >> 5, tt = t & 31;
        int c0 = (tt >> 2) * 2, r0 = (tt & 3) * 4;
        int rb = 32 * q + 16, cb = 32 * q;
        float a4[2][4] = {{0,0,0,0},{0,0,0,0}};
        for (int k = 0; k < 16; k += 4) {
            float4 xc0 = *(const float4*)&Amat[(cb + c0) * PITCH + cb + k];
            float4 xc1 = *(const float4*)&Amat[(cb + c0 + 1) * PITCH + cb + k];
#pragma unroll
            for (int rr = 0; rr < 4; ++rr) {
                float4 lr = *(const float4*)&Amat[(rb + r0 + rr) * PITCH + cb + k];
                a4[0][rr] += xc0.x * lr.x + xc0.y * lr.y + xc0.z * lr.z + xc0.w * lr.w;
                a4[1][rr] += xc1.x * lr.x + xc1.y * lr.y + xc1.z * lr.z + xc1.w * lr.w;
            }
        }
#pragma unroll
        for (int cc = 0; cc < 2; ++cc)
#pragma unroll
            for (int rr = 0; rr < 4; ++rr)
                Wb[q * 256 + (c0 + cc) * 16 + (r0 + rr)] = a4[cc][rr];
    }
    __syncthreads();
    for (int t = tid; t < 128; t += 256) {   // step B: X21^T = -(Yt * T2^T)
        int q = t >> 5, tt = t & 31;
        int c0 = (tt >> 2) * 2, r0 = (tt & 3) * 4;
        int rb = 32 * q + 16, cb = 32 * q;
        float a4[2][4] = {{0,0,0,0},{0,0,0,0}};
        for (int a = 0; a < 16; ++a) {
            float y0 = Wb[q * 256 + c0 * 16 + a];
            float y1 = Wb[q * 256 + (c0 + 1) * 16 + a];
            float4 t2 = *(const float4*)&Amat[(rb + a) * PITCH + rb + r0];
            a4[0][0] += y0 * t2.x; a4[0][1] += y0 * t2.y; a4[0][2] += y0 * t2.z; a4[0][3] += y0 * t2.w;
            a4[1][0] += y1 * t2.x; a4[1][1] += y1 * t2.y; a4[1][2] += y1 * t2.z; a4[1][3] += y1 * t2.w;
        }
#pragma unroll
        for (int cc = 0; cc < 2; ++cc)
#pragma unroll
            for (int rr = 0; rr < 4; ++rr)
                Amat[(cb + c0 + cc) * PITCH + rb + r0 + rr] = -a4[cc][rr];
    }
    __syncthreads();
    // Level 2: 32-super-pairs q=0..1
    {
        int q = tid >> 7, tt = tid & 127;
        int c0 = (tt >> 3) * 2, r0 = (tt & 7) * 4;
        int rb = 64 * q + 32, cb = 64 * q;
        int ks = c0 & ~15;
        float a4[2][4] = {{0,0,0,0},{0,0,0,0}};
        for (int k = ks; k < 32; k += 4) {
            float4 xc0 = *(const float4*)&Amat[(cb + c0) * PITCH + cb + k];
            float4 xc1 = *(const float4*)&Amat[(cb + c0 + 1) * PITCH + cb + k];
#pragma unroll
            for (int rr = 0; rr < 4; ++rr) {
                float4 lr = *(const float4*)&Amat[(rb + r0 + rr) * PITCH + cb + k];
                a4[0][rr] += xc0.x * lr.x + xc0.y * lr.y + xc0.z * lr.z + xc0.w * lr.w;
                a4[1][rr] += xc1.x * lr.x + xc1.y * lr.y + xc1.z * lr.z + xc1.w * lr.w;
            }
        }
#pragma unroll
        for (int cc = 0; cc < 2; ++cc)
#pragma unroll
            for (int rr = 0; rr < 4; ++rr)
                Wb[q * 1024 + (c0 + cc) * 32 + (r0 + rr)] = a4[cc][rr];
    }
    __syncthreads();
    {
        int q = tid >> 7, tt = tid & 127;
        int c0 = (tt >> 3) * 2, r0 = (tt & 7) * 4;
        int rb = 64 * q + 32, cb = 64 * q;
        int atop = (r0 & ~15) + 15;
        float a4[2][4] = {{0,0,0,0},{0,0,0,0}};
        for (int a = 0; a <= atop; ++a) {
            float y0 = Wb[q * 1024 + c0 * 32 + a];
            float y1 = Wb[q * 1024 + (c0 + 1) * 32 + a];
            float4 t2 = *(const float4*)&Amat[(rb + a) * PITCH + rb + r0];
            a4[0][0] += y0 * t2.x; a4[0][1] += y0 * t2.y; a4[0][2] += y0 * t2.z; a4[0][3] += y0 * t2.w;
            a4[1][0] += y1 * t2.x; a4[1][1] += y1 * t2.y; a4[1][2] += y1 * t2.z; a4[1][3] += y1 * t2.w;
        }
#pragma unroll
        for (int cc = 0; cc < 2; ++cc)
#pragma unroll
            for (int rr = 0; rr < 4; ++rr)
                Amat[(cb + c0 + cc) * PITCH + rb + r0 + rr] = -a4[cc][rr];
    }
    __syncthreads();
    // Level 3: 64-pair, two column halves
#pragma unroll
    for (int h3 = 0; h3 < 2; ++h3) {
        const int ch = 32 * h3;
        {
            int c0 = (tid >> 4) * 2, r0 = (tid & 15) * 4;
            int ks = (ch + c0) & ~15;
            float a4[2][4] = {{0,0,0,0},{0,0,0,0}};
            for (int k = ks; k < 64; k += 4) {
                float4 xc0 = *(const float4*)&Amat[(ch + c0) * PITCH + k];
                float4 xc1 = *(const float4*)&Amat[(ch + c0 + 1) * PITCH + k];
#pragma unroll
                for (int rr = 0; rr < 4; ++rr) {
                    float4 lr = *(const float4*)&Amat[(64 + r0 + rr) * PITCH + k];
                    a4[0][rr] += xc0.x * lr.x + xc0.y * lr.y + xc0.z * lr.z + xc0.w * lr.w;
                    a4[1][rr] += xc1.x * lr.x + xc1.y * lr.y + xc1.z * lr.z + xc1.w * lr.w;
                }
            }
#pragma unroll
            for (int cc = 0; cc < 2; ++cc)
#pragma unroll
                for (int rr = 0; rr < 4; ++rr)
                    Wb[(c0 + cc) * 64 + r0 + rr] = a4[cc][rr];
        }
        __syncthreads();
        {
            int c0 = (tid >> 4) * 2, r0 = (tid & 15) * 4;
            int atop = (r0 & ~15) + 15;
            float a4[2][4] = {{0,0,0,0},{0,0,0,0}};
            for (int a = 0; a <= atop; ++a) {
                float y0 = Wb[c0 * 64 + a];
                float y1 = Wb[(c0 + 1) * 64 + a];
                float4 t2 = *(const float4*)&Amat[(64 + a) * PITCH + 64 + r0];
                a4[0][0] += y0 * t2.x; a4[0][1] += y0 * t2.y; a4[0][2] += y0 * t2.z; a4[0][3] += y0 * t2.w;
                a4[1][0] += y1 * t2.x; a4[1][1] += y1 * t2.y; a4[1][2] += y1 * t2.z; a4[1][3] += y1 * t2.w;
            }
#pragma unroll
            for (int cc = 0; cc < 2; ++cc)
#pragma unroll
                for (int rr = 0; rr < 4; ++rr)
                    Amat[(ch + c0 + cc) * PITCH + 64 + r0 + rr] = -a4[cc][rr];
        }
        __syncthreads();
    }
    // ---- phase 4: trinv, qv, qd (one batched reduction)
    float v3[3] = {0.f, 0.f, 0.f};
    {
        int i = tid & 127, h = tid >> 7;
        int c0 = (i >> 4) << 4;
        int half = (128 - c0) >> 1;
        const float* Ar = &Amat[i * PITCH + c0 + h * half];
        for (int k2 = 0; k2 < half; k2 += 4) {
            float4 a = *(const float4*)&Ar[k2];
            v3[0] += a.x * a.x + a.y * a.y + a.z * a.z + a.w * a.w;
        }
    }
    if (tid < 128) {
        float a = zv[tid];  v3[1] = a * a;
        float d22 = zd[tid]; v3[2] = d22 * d22;
    }
    bsumN<3>(v3, red);
    if (tid == 0) {
        float n = 1.f + nv;
        float Aterm = trP - vsv / n;              // tr(Sq^{-1} Sp)
        float Bt = v3[0] + v3[1];                 // tr(Sp^{-1} Sq)
        float mq = dds - vds * vds / n;           // delta^T Sq^{-1} delta
        out[bid] = 0.25f * (Aterm + Bt - 256.f + mq + v3[2]);
    }
}

// ---------------------------------------------------------------- launch
extern "C" void kernel_launch(void* const* d_in, const int* in_sizes, int n_in,
                              void* d_out, int out_size, void* d_ws, size_t ws_size,
                              hipStream_t stream) {
    const float* wfm = (const float*)d_in[0];
    const float* wfd = (const float*)d_in[1];
    const float* sfm = (const float*)d_in[2];
    const float* sfd = (const float*)d_in[3];
    const float* W1 = (const float*)d_in[4];
    const float* B1 = (const float*)d_in[5];
    const float* W2 = (const float*)d_in[6];
    const float* B2 = (const float*)d_in[7];
    const float* W3 = (const float*)d_in[8];
    const float* B3 = (const float*)d_in[9];
    const float* W4 = (const float*)d_in[10];
    const float* B4 = (const float*)d_in[11];
    const float* lm = (const float*)d_in[12];
    const float* ldv = (const float*)d_in[13];
    float* out = (float*)d_out;
    float* ws = (float*)d_ws;

    float* wm = ws;                           // 262144
    float* wv = ws + 262144;                  // 262144
    float* sm = ws + 524288;                  // 1024
    float* sv = ws + 525312;                  // 1024
    float4* labscg = (float4*)(ws + 526336);  // 64 float4
    unsigned short* wvTg = (unsigned short*)(ws + 731392);  // 262144 bf16

    constexpr int SH_FLOATS = 19800;
    constexpr size_t SH_BYTES = SH_FLOATS * sizeof(float);   // 79200 B -> 2 blocks/CU
    (void)hipFuncSetAttribute((const void*)k4_fused,
                              hipFuncAttributeMaxDynamicSharedMemorySize,
                              (int)SH_BYTES);

    k1_gemm<<<dim3(258, 2), 256, 0, stream>>>(wfm, wfd, sfm, sfd,
                                              W1, B1, W2, B2, W3, B3, W4, B4,
                                              lm, ldv, wm, wv, sm, sv, labscg, wvTg);
    k4_fused<<<512, 256, SH_BYTES, stream>>>(wm, wv, wvTg, sm, sv, lm, ldv, labscg, out);
}

// Round 17
// 173.612 us; speedup vs baseline: 1.2354x; 1.2354x over previous
//
#include <hip/hip_runtime.h>
#include <hip/hip_bf16.h>

// B=8 S=256 H=768 D=128 L=64, all inputs f32.
// Outputs: relate_score (8*64) | lm_b (8*64*128) | lc_b (8*64*128*128), f32.

#define PITCH 132

typedef __attribute__((ext_vector_type(8))) short bf16x8;
typedef __attribute__((ext_vector_type(4))) float f32x4;

__device__ __forceinline__ float bf2f(unsigned int u) {
    union { unsigned int i; float f; } c; c.i = u << 16; return c.f;
}
__device__ __forceinline__ unsigned short f2bf(float f) {
    __hip_bfloat16 h = __float2bfloat16(f);
    union { __hip_bfloat16 h; unsigned short u; } c; c.h = h; return c.u;
}

// ---------------------------------------------------------------- K1: wm/wv GEMM (+ bf16 wv^T) + sm/sv (x==256) + label scalars (x==257)
__global__ __launch_bounds__(256, 2)
void k1_gemm(const float* __restrict__ Am, const float* __restrict__ Av,
             const float* __restrict__ sfm, const float* __restrict__ sfd,
             const float* __restrict__ W1, const float* __restrict__ B1,
             const float* __restrict__ W2, const float* __restrict__ B2,
             const float* __restrict__ W3, const float* __restrict__ B3,
             const float* __restrict__ W4, const float* __restrict__ B4,
             const float* __restrict__ lm, const float* __restrict__ ldv,
             float* __restrict__ wm, float* __restrict__ wv,
             float* __restrict__ sm, float* __restrict__ sv,
             float4* __restrict__ labscg,
             unsigned short* __restrict__ wvTg) {
    const int tid = threadIdx.x;
    const int sel = blockIdx.y;
    if (blockIdx.x == 257) {           // label scalars: mmp, |v|^2, vmp per label
        if (sel == 0) {
            int l = tid >> 2, q = tid & 3;
            const float* mr = lm + (size_t)l * 128 + q * 32;
            const float* vr = ldv + (size_t)l * 128 + q * 32;
            float s0 = 0.f, s1 = 0.f, s2 = 0.f;
            for (int k = 0; k < 32; k += 4) {
                float4 m = *(const float4*)&mr[k];
                float4 v = *(const float4*)&vr[k];
                s0 += m.x * m.x + m.y * m.y + m.z * m.z + m.w * m.w;
                s1 += v.x * v.x + v.y * v.y + v.z * v.z + v.w * v.w;
                s2 += m.x * v.x + m.y * v.y + m.z * v.z + m.w * v.w;
            }
            s0 += __shfl_xor(s0, 1); s0 += __shfl_xor(s0, 2);
            s1 += __shfl_xor(s1, 1); s1 += __shfl_xor(s1, 2);
            s2 += __shfl_xor(s2, 1); s2 += __shfl_xor(s2, 2);
            if (q == 0) labscg[l] = make_float4(s0, s1, s2, 0.f);
        }
        return;
    }
    __shared__ float At[8][64];
    __shared__ __align__(16) float Wt[64][128];
    __shared__ float tileT[8][129];
    const bool sentB = (blockIdx.x == 256);
    const float* A  = sentB ? (sel ? sfd : sfm) : (sel ? Av : Am);
    const float* W  = sentB ? (sel ? W4 : W3) : (sel ? W2 : W1);
    const float* Bs = sentB ? (sel ? B4 : B3) : (sel ? B2 : B1);
    float* D = sentB ? (sel ? sv : sm) : (sel ? wv : wm);
    const int R0 = sentB ? 0 : blockIdx.x * 8;
    const int r = tid >> 5;
    const int j0 = (tid & 31) * 4;
    float acc[4] = {0.f, 0.f, 0.f, 0.f};
    for (int k0 = 0; k0 < 768; k0 += 64) {
        __syncthreads();
        {
            int f = tid;
            At[f >> 6][f & 63] = A[(size_t)(R0 + (f >> 6)) * 768 + k0 + (f & 63)];
            f = tid + 256;
            At[f >> 6][f & 63] = A[(size_t)(R0 + (f >> 6)) * 768 + k0 + (f & 63)];
        }
#pragma unroll
        for (int it = 0; it < 8; ++it) {
            int f = tid + it * 256;
            int rr = f >> 5, c4 = (f & 31) * 4;
            *(float4*)&Wt[rr][c4] = *(const float4*)&W[(size_t)(k0 + rr) * 128 + c4];
        }
        __syncthreads();
#pragma unroll 16
        for (int kk = 0; kk < 64; ++kk) {
            float a = At[r][kk];
            float4 w0 = *(const float4*)&Wt[kk][j0];
            acc[0] += a * w0.x; acc[1] += a * w0.y; acc[2] += a * w0.z; acc[3] += a * w0.w;
        }
    }
    {
        float b0 = Bs[j0], b1 = Bs[j0 + 1], b2 = Bs[j0 + 2], b3 = Bs[j0 + 3];
        float4 o = make_float4(acc[0] + b0, acc[1] + b1, acc[2] + b2, acc[3] + b3);
        *(float4*)&D[(size_t)(R0 + r) * 128 + j0] = o;
        tileT[r][j0 + 0] = o.x; tileT[r][j0 + 1] = o.y;
        tileT[r][j0 + 2] = o.z; tileT[r][j0 + 3] = o.w;
    }
    if (sel && !sentB) {
        __syncthreads();
        if (tid < 128) {
            int d = tid;
            unsigned short u[8];
#pragma unroll
            for (int ss = 0; ss < 8; ++ss) u[ss] = f2bf(tileT[ss][d]);
            unsigned int p0 = (unsigned int)u[0] | ((unsigned int)u[1] << 16);
            unsigned int p1 = (unsigned int)u[2] | ((unsigned int)u[3] << 16);
            unsigned int p2 = (unsigned int)u[4] | ((unsigned int)u[5] << 16);
            unsigned int p3 = (unsigned int)u[6] | ((unsigned int)u[7] << 16);
            unsigned short* dst = wvTg + (size_t)(R0 >> 8) * 32768 + (size_t)d * 256 + (R0 & 255);
            *(uint4*)dst = make_uint4(p0, p1, p2, p3);
        }
    }
}

// ---------------------------------------------------------------- batched block reduce (4 waves), one barrier set
template <int N>
__device__ __forceinline__ void bsumN(float* v, float* red) {
#pragma unroll
    for (int o = 32; o; o >>= 1)
#pragma unroll
        for (int n = 0; n < N; ++n) v[n] += __shfl_xor(v[n], o);
    __syncthreads();
    if ((threadIdx.x & 63) == 0) {
        int w = threadIdx.x >> 6;
#pragma unroll
        for (int n = 0; n < N; ++n) red[w * N + n] = v[n];
    }
    __syncthreads();
#pragma unroll
    for (int n = 0; n < N; ++n)
        v[n] = red[0 * N + n] + red[1 * N + n] + red[2 * N + n] + red[3 * N + n];
    __syncthreads();
}

// ---------------------------------------------------------------- K4: fused; 2-barrier lookahead Cholesky + recursive-doubling inverse.
__global__ __launch_bounds__(256, 2)
void k4_fused(const float* __restrict__ wm, const float* __restrict__ wv,
              const unsigned short* __restrict__ wvTg,
              const float* __restrict__ smg, const float* __restrict__ svg,
              const float* __restrict__ lmg, const float* __restrict__ ldvg,
              const float4* __restrict__ labscg,
              float* __restrict__ out) {
    extern __shared__ float smem[];
    float* Amat = smem;                 // 16896 f32
    float* Wb   = smem + 16896;         // 2112 (RD temp alias)
    float* ssq  = smem + 19008;         // 256
    float* svr  = smem + 19264;         // 128
    float* vrow = smem + 19392;         // 128
    float* zv   = smem + 19520;         // 128  (mu until delta built)
    float* zd   = smem + 19648;         // 128
    float* red  = smem + 19776;         // 24
    float* scoreL = Amat;               // 256 (pre-staging only)
    float* vpart  = Amat + 256;         // 1024 (pre-staging only)

    const int tid = threadIdx.x;
    const int bid = blockIdx.x;
    const int b = bid >> 6, l = bid & 63;

    if (tid < 128) {
        svr[tid]  = svg[b * 128 + tid];
        vrow[tid] = ldvg[l * 128 + tid];
        zv[tid]   = lmg[l * 128 + tid];     // mu (temporary)
    }
    __syncthreads();
    // ---- early output writes: lm_b[b][l], lc_b[b][l]
    if (tid < 32) {
        float4 v = *(const float4*)&lmg[l * 128 + tid * 4];
        *(float4*)&out[512 + (size_t)bid * 128 + tid * 4] = v;
    }
    {
        float* lcb = out + 512 + 65536 + (size_t)bid * 16384;
#pragma unroll
        for (int q = 0; q < 16; ++q) {
            int flat4 = q * 256 + tid;
            int i = flat4 >> 5;
            int j4 = (flat4 & 31) * 4;
            float vi = vrow[i];
            float4 r;
            r.x = vi * vrow[j4 + 0] + ((i == j4 + 0) ? 1.f : 0.f);
            r.y = vi * vrow[j4 + 1] + ((i == j4 + 1) ? 1.f : 0.f);
            r.z = vi * vrow[j4 + 2] + ((i == j4 + 2) ? 1.f : 0.f);
            r.w = vi * vrow[j4 + 3] + ((i == j4 + 3) ? 1.f : 0.f);
            *(float4*)&lcb[(size_t)flat4 * 4] = r;
        }
    }
    // ---- phase 0a: label scalars (precomputed in k1)
    float4 lsv = labscg[l];
    const float mmp = lsv.x, np = 1.f + lsv.y, vmp = lsv.z;
    // ---- phase 0b: per-row dots + row scalars (thread = s)
    const float4* wmr = (const float4*)(wm + (size_t)(b * 256 + tid) * 128);
    const float4* wvr = (const float4*)(wv + (size_t)(b * 256 + tid) * 128);
    float md = 0.f, dot = 0.f, pvv = 0.f, vq = 0.f;
    float smm = 0.f, svv = 0.f, smv = 0.f;
#pragma unroll 8
    for (int q = 0; q < 32; ++q) {
        float4 xm = wmr[q], xv = wvr[q];
        const float* m4 = &zv[q * 4];
        const float* v4 = &vrow[q * 4];
        md  += m4[0] * xm.x + m4[1] * xm.y + m4[2] * xm.z + m4[3] * xm.w;
        dot += v4[0] * xv.x + v4[1] * xv.y + v4[2] * xv.z + v4[3] * xv.w;
        pvv += m4[0] * xv.x + m4[1] * xv.y + m4[2] * xv.z + m4[3] * xv.w;
        vq  += v4[0] * xm.x + v4[1] * xm.y + v4[2] * xm.z + v4[3] * xm.w;
        smm += xm.x * xm.x + xm.y * xm.y + xm.z * xm.z + xm.w * xm.w;
        svv += xv.x * xv.x + xv.y * xv.y + xv.z * xv.z + xv.w * xv.w;
        smv += xm.x * xv.x + xm.y * xv.y + xm.z * xv.z + xm.w * xv.w;
    }
    float nq = 1.f + svv;
    float d2 = smm - 2.f * md + mmp;
    float vqd = smv - pvv, vpd = vq - vmp;
    float inq = 1.f / nq, inp = 1.f / np;
    float maha_q = d2 - vqd * vqd * inq;
    float maha_p = d2 - vpd * vpd * inp;
    float logit = 0.25f * ((np - 1.f) + (nq - 1.f)
                           - (nq - 1.f + dot * dot) * inq
                           - (np - 1.f + dot * dot) * inp
                           + maha_q + maha_p);
    // ---- phase 0c: softmax over 256 threads (2 barriers: distinct red slots)
    float mx = logit;
#pragma unroll
    for (int o = 32; o; o >>= 1) mx = fmaxf(mx, __shfl_xor(mx, o));
    if ((tid & 63) == 0) red[tid >> 6] = mx;
    __syncthreads();
    mx = fmaxf(fmaxf(red[0], red[1]), fmaxf(red[2], red[3]));
    float e = expf(logit - mx);
    float s = e;
#pragma unroll
    for (int o = 32; o; o >>= 1) s += __shfl_xor(s, o);
    if ((tid & 63) == 0) red[8 + (tid >> 6)] = s;
    __syncthreads();
    float tot = red[8] + red[9] + red[10] + red[11];
    float sc = e / tot;
    scoreL[tid] = sc;
    ssq[tid] = sqrtf(sc);
    __syncthreads();
    // ---- phase 0d: v_mean = score @ wm
    {
        int d4 = (tid & 31) * 4, sg = tid >> 5;
        const float* wmb = wm + (size_t)b * 256 * 128;
        float ax = 0.f, ay = 0.f, az = 0.f, aw = 0.f;
        for (int s2 = sg * 32; s2 < sg * 32 + 32; ++s2) {
            float w = scoreL[s2];
            float4 x = *(const float4*)&wmb[(size_t)s2 * 128 + d4];
            ax += w * x.x; ay += w * x.y; az += w * x.z; aw += w * x.w;
        }
        *(float4*)&vpart[sg * 128 + d4] = make_float4(ax, ay, az, aw);
    }
    __syncthreads();
    if (tid < 128) {
        float vm8 = 0.f;
#pragma unroll
        for (int g2 = 0; g2 < 8; ++g2) vm8 += vpart[g2 * 128 + tid];
        zd[tid] = zv[tid] - 0.5f * (smg[b * 128 + tid] + vm8);  // delta
        zv[tid] = vrow[tid];                                     // rhs v
    }
    __syncthreads();
    // ---- phase 1a: stage S^T (bf16, rows d, 264-bf16 pitch), scaled by sqrt(score)
    {
        unsigned short* Sb = (unsigned short*)Amat;
        const unsigned short* src = wvTg + (size_t)b * 32768;
        const int s0 = (tid & 31) * 8;
        float ssv[8];
#pragma unroll
        for (int j = 0; j < 8; ++j) ssv[j] = ssq[s0 + j];
#pragma unroll
        for (int it = 0; it < 16; ++it) {
            int f8 = tid + it * 256;
            int d = f8 >> 5;
            uint4 raw = *(const uint4*)&src[(size_t)f8 * 8];
            unsigned int p0 = (unsigned int)f2bf(bf2f(raw.x & 0xffffu) * ssv[0])
                            | ((unsigned int)f2bf(bf2f(raw.x >> 16) * ssv[1]) << 16);
            unsigned int p1 = (unsigned int)f2bf(bf2f(raw.y & 0xffffu) * ssv[2])
                            | ((unsigned int)f2bf(bf2f(raw.y >> 16) * ssv[3]) << 16);
            unsigned int p2 = (unsigned int)f2bf(bf2f(raw.z & 0xffffu) * ssv[4])
                            | ((unsigned int)f2bf(bf2f(raw.z >> 16) * ssv[5]) << 16);
            unsigned int p3 = (unsigned int)f2bf(bf2f(raw.w & 0xffffu) * ssv[6])
                            | ((unsigned int)f2bf(bf2f(raw.w >> 16) * ssv[7]) << 16);
            *(uint4*)&Sb[(size_t)d * 264 + s0] = make_uint4(p0, p1, p2, p3);
        }
    }
    __syncthreads();
    // ---- phase 1b: M = S^T S via MFMA; wave w computes tile-rows w and w+4
    {
        const unsigned short* Sb = (const unsigned short*)Amat;
        const int w = tid >> 6, ln = tid & 63;
        const int rl = ln & 15, g = ln >> 4;
        const int arow0 = 16 * w + rl;
        const int arow1 = 16 * (w + 4) + rl;
        f32x4 acc0[8], acc1[8];
#pragma unroll
        for (int t = 0; t < 8; ++t) {
            acc0[t] = (f32x4){0.f, 0.f, 0.f, 0.f};
            acc1[t] = (f32x4){0.f, 0.f, 0.f, 0.f};
        }
#pragma unroll
        for (int ks = 0; ks < 8; ++ks) {
            bf16x8 a0 = *(const bf16x8*)&Sb[(size_t)arow0 * 264 + ks * 32 + g * 8];
            bf16x8 a1 = *(const bf16x8*)&Sb[(size_t)arow1 * 264 + ks * 32 + g * 8];
#pragma unroll
            for (int tj = 0; tj < 8; ++tj) {
                bf16x8 bb = *(const bf16x8*)&Sb[(size_t)(16 * tj + rl) * 264 + ks * 32 + g * 8];
                acc0[tj] = __builtin_amdgcn_mfma_f32_16x16x32_bf16(a0, bb, acc0[tj], 0, 0, 0);
                acc1[tj] = __builtin_amdgcn_mfma_f32_16x16x32_bf16(a1, bb, acc1[tj], 0, 0, 0);
            }
        }
        __syncthreads();
#pragma unroll
        for (int tj = 0; tj < 8; ++tj) {
            int j = 16 * tj + rl;
            float svj = svr[j];
#pragma unroll
            for (int r = 0; r < 4; ++r) {
                int i = 16 * w + g * 4 + r;
                Amat[i * PITCH + j] = ((i == j) ? 1.f : 0.f) + 0.5f * (svr[i] * svj + acc0[tj][r]);
                int i2 = 16 * (w + 4) + g * 4 + r;
                Amat[i2 * PITCH + j] = ((i2 == j) ? 1.f : 0.f) + 0.5f * (svr[i2] * svj + acc1[tj][r]);
            }
        }
    }
    __syncthreads();
    // ---- phase 2c: label-side closed-form terms, one batched reduction
    float v5[5] = {0.f, 0.f, 0.f, 0.f, 0.f};
    if (tid < 128) {
        v5[0] = Amat[tid * PITCH + tid];
        float vv = vrow[tid], de = zd[tid];
        v5[1] = vv * vv; v5[2] = de * de; v5[3] = vv * de;
    }
    {
        int i = tid >> 1, h = tid & 1;
        const float* Ar = &Amat[i * PITCH + h * 64];
        const float* vr = &vrow[h * 64];
        float s2 = 0.f;
        for (int k2 = 0; k2 < 64; k2 += 4) {
            float4 a = *(const float4*)&Ar[k2];
            s2 += a.x * vr[k2] + a.y * vr[k2 + 1] + a.z * vr[k2 + 2] + a.w * vr[k2 + 3];
        }
        v5[4] = vrow[i] * s2;
    }
    bsumN<5>(v5, red);
    const float trP = v5[0], nv = v5[1], dds = v5[2], vds = v5[3], vsv = v5[4];
    // ---- phase 3: blocked Cholesky, 2 barriers/panel.
    for (int p = 0; p < 8; ++p) {
        const int base = 16 * p;
        const int R = 112 - base;
        __syncthreads();                         // solve(p-1)/Wb(p-1)/z'(p-1) visible
        if (tid < 64) {
            const int c = tid;
            float cv[16];
            if (c < 16) {
#pragma unroll
                for (int r2 = 0; r2 < 16; ++r2) {
                    int hi = (r2 >= c) ? r2 : c, lo2 = (r2 >= c) ? c : r2;
                    cv[r2] = Amat[(base + hi) * PITCH + base + lo2];
                }
                if (p > 0) {
                    float wbc[16];
#pragma unroll
                    for (int t = 0; t < 16; ++t) wbc[t] = Wb[t * PITCH + base + c];
#pragma unroll
                    for (int r2 = 0; r2 < 16; ++r2) {
                        float acc2 = 0.f;
#pragma unroll
                        for (int t = 0; t < 16; ++t)
                            acc2 += __shfl(wbc[t], r2) * wbc[t];
                        cv[r2] -= acc2;
                    }
                }
            } else {
#pragma unroll
                for (int r2 = 0; r2 < 16; ++r2) cv[r2] = 0.f;
            }
#pragma unroll
            for (int t = 0; t < 16; ++t) {
                float lt[16];
#pragma unroll
                for (int r2 = 0; r2 < 16; ++r2) lt[r2] = __shfl(cv[r2], t);
                float invs = 1.f / sqrtf(lt[t]);
                if (c == t) {
#pragma unroll
                    for (int r2 = 0; r2 < 16; ++r2) cv[r2] = (r2 >= t) ? lt[r2] * invs : 0.f;
                } else if (c > t && c < 16) {
                    float lc = lt[c] * invs;
#pragma unroll
                    for (int r2 = 0; r2 < 16; ++r2)
                        if (r2 > t) cv[r2] -= (lt[r2] * invs) * lc;
                }
            }
            float x[16], acb[16];
#pragma unroll
            for (int r2 = 0; r2 < 16; ++r2) acb[r2] = 0.f;
#pragma unroll
            for (int r2 = 0; r2 < 16; ++r2) {
                float Lrr = __shfl(cv[r2], r2);
                float xr = (((c == r2) ? 1.f : 0.f) - acb[r2]) / Lrr;
                x[r2] = xr;
#pragma unroll
                for (int q = r2 + 1; q < 16; ++q) acb[q] += __shfl(cv[q], r2) * xr;
            }
            if (c < 16) {
#pragma unroll
                for (int r2 = 0; r2 < 16; ++r2)
                    Amat[(base + c) * PITCH + base + r2] = x[r2];   // T^T into diag block
            }
        } else if (p > 0) {
            const int pb = base - 16;
            int t = tid - 64;                    // 0..191
            if (t < 128 - base) {                // z trailing update, rows base..127
                int i = base + t;
                const float* Lr = &Amat[i * PITCH + pb];
                float dv = 0.f, dd2 = 0.f;
#pragma unroll
                for (int t2 = 0; t2 < 16; ++t2) {
                    float lvv = Lr[t2];
                    dv  += lvv * zv[pb + t2];
                    dd2 += lvv * zd[pb + t2];
                }
                zv[i] -= dv; zd[i] -= dd2;
            }
            // U_col-below: rows base+16..127, cols base..base+15
            for (int idx = t; idx < R * 16; idx += 192) {
                int r2 = idx >> 4, jc = idx & 15;
                int i = base + 16 + r2, j = base + jc;
                const float* wi = &Wb[i];
                const float* wj = &Wb[j];
                float acc2 = 0.f;
#pragma unroll
                for (int t2 = 0; t2 < 16; ++t2)
                    acc2 += wi[t2 * PITCH] * wj[t2 * PITCH];
                Amat[i * PITCH + j] -= acc2;
            }
            // U_rest: lower 8x8 tiles, rows/cols >= base+16
            if (R > 0) {
                int nt = R >> 3;
                int ntri = (nt * (nt + 1)) >> 1;
                for (int tau = t; tau < ntri; tau += 192) {
                    float ft = sqrtf(8.f * (float)tau + 1.f);
                    int tr = (int)((ft - 1.f) * 0.5f);
                    while (((tr + 1) * (tr + 2)) / 2 <= tau) ++tr;
                    while ((tr * (tr + 1)) / 2 > tau) --tr;
                    int tc = tau - ((tr * (tr + 1)) >> 1);
                    int ii = base + 16 + tr * 8, jj = base + 16 + tc * 8;
                    float a2[8][8];
#pragma unroll
                    for (int r2 = 0; r2 < 8; ++r2)
#pragma unroll
                        for (int c2 = 0; c2 < 8; ++c2) a2[r2][c2] = 0.f;
#pragma unroll
                    for (int t2 = 0; t2 < 16; ++t2) {
                        const float* wr = &Wb[t2 * PITCH];
                        float4 x0 = *(const float4*)&wr[ii];
                        float4 x1 = *(const float4*)&wr[ii + 4];
                        float4 y0 = *(const float4*)&wr[jj];
                        float4 y1 = *(const float4*)&wr[jj + 4];
                        float xa[8] = {x0.x,x0.y,x0.z,x0.w, x1.x,x1.y,x1.z,x1.w};
                        float yb[8] = {y0.x,y0.y,y0.z,y0.w, y1.x,y1.y,y1.z,y1.w};
#pragma unroll
                        for (int r2 = 0; r2 < 8; ++r2)
#pragma unroll
                            for (int c2 = 0; c2 < 8; ++c2) a2[r2][c2] += xa[r2] * yb[c2];
                    }
#pragma unroll
                    for (int r2 = 0; r2 < 8; ++r2) {
                        float* Ar2 = &Amat[(ii + r2) * PITCH + jj];
                        float4 u0 = *(float4*)&Ar2[0];
                        float4 u1 = *(float4*)&Ar2[4];
                        u0.x -= a2[r2][0]; u0.y -= a2[r2][1]; u0.z -= a2[r2][2]; u0.w -= a2[r2][3];
                        u1.x -= a2[r2][4]; u1.y -= a2[r2][5]; u1.z -= a2[r2][6]; u1.w -= a2[r2][7];
                        *(float4*)&Ar2[0] = u0;
                        *(float4*)&Ar2[4] = u1;
                    }
                }
            }
        }
        __syncthreads();                         // T ready; updates applied
        if (R > 0 && tid < R) {
            int i = base + 16 + tid;
            const float* Ar = &Amat[i * PITCH + base];
            float4 q0 = *(const float4*)&Ar[0];
            float4 q1 = *(const float4*)&Ar[4];
            float4 q2 = *(const float4*)&Ar[8];
            float4 q3 = *(const float4*)&Ar[12];
            float rA[16] = {q0.x,q0.y,q0.z,q0.w, q1.x,q1.y,q1.z,q1.w,
                            q2.x,q2.y,q2.z,q2.w, q3.x,q3.y,q3.z,q3.w};
            float lo[16];
#pragma unroll
            for (int t = 0; t < 16; ++t) lo[t] = 0.f;
#pragma unroll
            for (int a = 0; a < 16; ++a) {
                float va = rA[a];
                const float* Trow = &Amat[(base + a) * PITCH + base];
                float4 t0 = *(const float4*)&Trow[0];
                float4 t1 = *(const float4*)&Trow[4];
                float4 t2 = *(const float4*)&Trow[8];
                float4 t3 = *(const float4*)&Trow[12];
                lo[0] += va * t0.x; lo[1] += va * t0.y; lo[2] += va * t0.z; lo[3] += va * t0.w;
                lo[4] += va * t1.x; lo[5] += va * t1.y; lo[6] += va * t1.z; lo[7] += va * t1.w;
                lo[8] += va * t2.x; lo[9] += va * t2.y; lo[10] += va * t2.z; lo[11] += va * t2.w;
                lo[12] += va * t3.x; lo[13] += va * t3.y; lo[14] += va * t3.z; lo[15] += va * t3.w;
            }
            float* Aw = &Amat[i * PITCH + base];
            *(float4*)&Aw[0]  = make_float4(lo[0], lo[1], lo[2], lo[3]);
            *(float4*)&Aw[4]  = make_float4(lo[4], lo[5], lo[6], lo[7]);
            *(float4*)&Aw[8]  = make_float4(lo[8], lo[9], lo[10], lo[11]);
            *(float4*)&Aw[12] = make_float4(lo[12], lo[13], lo[14], lo[15]);
#pragma unroll
            for (int t = 0; t < 16; ++t) Wb[t * PITCH + i] = lo[t];
        }
        if (tid >= 128 && tid < 160) {           // z' = T * z_panel (wave 2, lockstep)
            int t2 = (tid - 128) & 15;
            float* zp = (tid < 144) ? zv : zd;
            float a0 = 0.f;
#pragma unroll
            for (int a = 0; a < 16; ++a)
                a0 += Amat[(base + a) * PITCH + base + t2] * zp[base + a];
            zp[base + t2] = a0;
        }
    }
    // ---- phase 3b: X = L^{-1} via RECURSIVE DOUBLING (16 -> 32 -> 64 -> 128).
    __syncthreads();
    // Level 1: pairs q=0..3
    for (int t = tid; t < 128; t += 256) {   // step A: Yt = (L21*T1)^T
        int q = t >> 5, tt = t & 31;
        int c0 = (tt >> 2) * 2, r0 = (tt & 3) * 4;
        int rb = 32 * q + 16, cb = 32 * q;
        float a4[2][4] = {{0,0,0,0},{0,0,0,0}};
        for (int k = 0; k < 16; k += 4) {
            float4 xc0 = *(const float4*)&Amat[(cb + c0) * PITCH + cb + k];
            float4 xc1 = *(const float4*)&Amat[(cb + c0 + 1) * PITCH + cb + k];
#pragma unroll
            for (int rr = 0; rr < 4; ++rr) {
                float4 lr = *(const float4*)&Amat[(rb + r0 + rr) * PITCH + cb + k];
                a4[0][rr] += xc0.x * lr.x + xc0.y * lr.y + xc0.z * lr.z + xc0.w * lr.w;
                a4[1][rr] += xc1.x * lr.x + xc1.y * lr.y + xc1.z * lr.z + xc1.w * lr.w;
            }
        }
#pragma unroll
        for (int cc = 0; cc < 2; ++cc)
#pragma unroll
            for (int rr = 0; rr < 4; ++rr)
                Wb[q * 256 + (c0 + cc) * 16 + (r0 + rr)] = a4[cc][rr];
    }
    __syncthreads();
    for (int t = tid; t < 128; t += 256) {   // step B: X21^T = -(Yt * T2^T)
        int q = t >> 5, tt = t & 31;
        int c0 = (tt >> 2) * 2, r0 = (tt & 3) * 4;
        int rb = 32 * q + 16, cb = 32 * q;
        float a4[2][4] = {{0,0,0,0},{0,0,0,0}};
        for (int a = 0; a < 16; ++a) {
            float y0 = Wb[q * 256 + c0 * 16 + a];
            float y1 = Wb[q * 256 + (c0 + 1) * 16 + a];
            float4 t2 = *(const float4*)&Amat[(rb + a) * PITCH + rb + r0];
            a4[0][0] += y0 * t2.x; a4[0][1] += y0 * t2.y; a4[0][2] += y0 * t2.z; a4[0][3] += y0 * t2.w;
            a4[1][0] += y1 * t2.x; a4[1][1] += y1 * t2.y; a4[1][2] += y1 * t2.z; a4[1][3] += y1 * t2.w;
        }
#pragma unroll
        for (int cc = 0; cc < 2; ++cc)
#pragma unroll
            for (int rr = 0; rr < 4; ++rr)
                Amat[(cb + c0 + cc) * PITCH + rb + r0 + rr] = -a4[cc][rr];
    }
    __syncthreads();
    // Level 2: 32-super-pairs q=0..1
    {
        int q = tid >> 7, tt = tid & 127;
        int c0 = (tt >> 3) * 2, r0 = (tt & 7) * 4;
        int rb = 64 * q + 32, cb = 64 * q;
        int ks = c0 & ~15;
        float a4[2][4] = {{0,0,0,0},{0,0,0,0}};
        for (int k = ks; k < 32; k += 4) {
            float4 xc0 = *(const float4*)&Amat[(cb + c0) * PITCH + cb + k];
            float4 xc1 = *(const float4*)&Amat[(cb + c0 + 1) * PITCH + cb + k];
#pragma unroll
            for (int rr = 0; rr < 4; ++rr) {
                float4 lr = *(const float4*)&Amat[(rb + r0 + rr) * PITCH + cb + k];
                a4[0][rr] += xc0.x * lr.x + xc0.y * lr.y + xc0.z * lr.z + xc0.w * lr.w;
                a4[1][rr] += xc1.x * lr.x + xc1.y * lr.y + xc1.z * lr.z + xc1.w * lr.w;
            }
        }
#pragma unroll
        for (int cc = 0; cc < 2; ++cc)
#pragma unroll
            for (int rr = 0; rr < 4; ++rr)
                Wb[q * 1024 + (c0 + cc) * 32 + (r0 + rr)] = a4[cc][rr];
    }
    __syncthreads();
    {
        int q = tid >> 7, tt = tid & 127;
        int c0 = (tt >> 3) * 2, r0 = (tt & 7) * 4;
        int rb = 64 * q + 32, cb = 64 * q;
        int atop = (r0 & ~15) + 15;
        float a4[2][4] = {{0,0,0,0},{0,0,0,0}};
        for (int a = 0; a <= atop; ++a) {
            float y0 = Wb[q * 1024 + c0 * 32 + a];
            float y1 = Wb[q * 1024 + (c0 + 1) * 32 + a];
            float4 t2 = *(const float4*)&Amat[(rb + a) * PITCH + rb + r0];
            a4[0][0] += y0 * t2.x; a4[0][1] += y0 * t2.y; a4[0][2] += y0 * t2.z; a4[0][3] += y0 * t2.w;
            a4[1][0] += y1 * t2.x; a4[1][1] += y1 * t2.y; a4[1][2] += y1 * t2.z; a4[1][3] += y1 * t2.w;
        }
#pragma unroll
        for (int cc = 0; cc < 2; ++cc)
#pragma unroll
            for (int rr = 0; rr < 4; ++rr)
                Amat[(cb + c0 + cc) * PITCH + rb + r0 + rr] = -a4[cc][rr];
    }
    __syncthreads();
    // Level 3: 64-pair, two column halves
#pragma unroll
    for (int h3 = 0; h3 < 2; ++h3) {
        const int ch = 32 * h3;
        {
            int c0 = (tid >> 4) * 2, r0 = (tid & 15) * 4;
            int ks = (ch + c0) & ~15;
            float a4[2][4] = {{0,0,0,0},{0,0,0,0}};
            for (int k = ks; k < 64; k += 4) {
                float4 xc0 = *(const float4*)&Amat[(ch + c0) * PITCH + k];
                float4 xc1 = *(const float4*)&Amat[(ch + c0 + 1) * PITCH + k];
#pragma unroll
                for (int rr = 0; rr < 4; ++rr) {
                    float4 lr = *(const float4*)&Amat[(64 + r0 + rr) * PITCH + k];
                    a4[0][rr] += xc0.x * lr.x + xc0.y * lr.y + xc0.z * lr.z + xc0.w * lr.w;
                    a4[1][rr] += xc1.x * lr.x + xc1.y * lr.y + xc1.z * lr.z + xc1.w * lr.w;
                }
            }
#pragma unroll
            for (int cc = 0; cc < 2; ++cc)
#pragma unroll
                for (int rr = 0; rr < 4; ++rr)
                    Wb[(c0 + cc) * 64 + r0 + rr] = a4[cc][rr];
        }
        __syncthreads();
        {
            int c0 = (tid >> 4) * 2, r0 = (tid & 15) * 4;
            int atop = (r0 & ~15) + 15;
            float a4[2][4] = {{0,0,0,0},{0,0,0,0}};
            for (int a = 0; a <= atop; ++a) {
                float y0 = Wb[c0 * 64 + a];
                float y1 = Wb[(c0 + 1) * 64 + a];
                float4 t2 = *(const float4*)&Amat[(64 + a) * PITCH + 64 + r0];
                a4[0][0] += y0 * t2.x; a4[0][1] += y0 * t2.y; a4[0][2] += y0 * t2.z; a4[0][3] += y0 * t2.w;
                a4[1][0] += y1 * t2.x; a4[1][1] += y1 * t2.y; a4[1][2] += y1 * t2.z; a4[1][3] += y1 * t2.w;
            }
#pragma unroll
            for (int cc = 0; cc < 2; ++cc)
#pragma unroll
                for (int rr = 0; rr < 4; ++rr)
                    Amat[(ch + c0 + cc) * PITCH + 64 + r0 + rr] = -a4[cc][rr];
        }
        __syncthreads();
    }
    // ---- phase 4: trinv, qv, qd (one batched reduction)
    float v3[3] = {0.f, 0.f, 0.f};
    {
        int i = tid & 127, h = tid >> 7;
        int c0 = (i >> 4) << 4;
        int half = (128 - c0) >> 1;
        const float* Ar = &Amat[i * PITCH + c0 + h * half];
        for (int k2 = 0; k2 < half; k2 += 4) {
            float4 a = *(const float4*)&Ar[k2];
            v3[0] += a.x * a.x + a.y * a.y + a.z * a.z + a.w * a.w;
        }
    }
    if (tid < 128) {
        float a = zv[tid];  v3[1] = a * a;
        float d22 = zd[tid]; v3[2] = d22 * d22;
    }
    bsumN<3>(v3, red);
    if (tid == 0) {
        float n = 1.f + nv;
        float Aterm = trP - vsv / n;              // tr(Sq^{-1} Sp)
        float Bt = v3[0] + v3[1];                 // tr(Sp^{-1} Sq)
        float mq = dds - vds * vds / n;           // delta^T Sq^{-1} delta
        out[bid] = 0.25f * (Aterm + Bt - 256.f + mq + v3[2]);
    }
}

// ---------------------------------------------------------------- launch
extern "C" void kernel_launch(void* const* d_in, const int* in_sizes, int n_in,
                              void* d_out, int out_size, void* d_ws, size_t ws_size,
                              hipStream_t stream) {
    const float* wfm = (const float*)d_in[0];
    const float* wfd = (const float*)d_in[1];
    const float* sfm = (const float*)d_in[2];
    const float* sfd = (const float*)d_in[3];
    const float* W1 = (const float*)d_in[4];
    const float* B1 = (const float*)d_in[5];
    const float* W2 = (const float*)d_in[6];
    const float* B2 = (const float*)d_in[7];
    const float* W3 = (const float*)d_in[8];
    const float* B3 = (const float*)d_in[9];
    const float* W4 = (const float*)d_in[10];
    const float* B4 = (const float*)d_in[11];
    const float* lm = (const float*)d_in[12];
    const float* ldv = (const float*)d_in[13];
    float* out = (float*)d_out;
    float* ws = (float*)d_ws;

    float* wm = ws;                           // 262144
    float* wv = ws + 262144;                  // 262144
    float* sm = ws + 524288;                  // 1024
    float* sv = ws + 525312;                  // 1024
    float4* labscg = (float4*)(ws + 526336);  // 64 float4
    unsigned short* wvTg = (unsigned short*)(ws + 731392);  // 262144 bf16

    constexpr int SH_FLOATS = 19800;
    constexpr size_t SH_BYTES = SH_FLOATS * sizeof(float);   // 79200 B -> 2 blocks/CU
    (void)hipFuncSetAttribute((const void*)k4_fused,
                              hipFuncAttributeMaxDynamicSharedMemorySize,
                              (int)SH_BYTES);

    k1_gemm<<<dim3(258, 2), 256, 0, stream>>>(wfm, wfd, sfm, sfd,
                                              W1, B1, W2, B2, W3, B3, W4, B4,
                                              lm, ldv, wm, wv, sm, sv, labscg, wvTg);
    k4_fused<<<512, 256, SH_BYTES, stream>>>(wm, wv, wvTg, sm, sv, lm, ldv, labscg, out);
}